// Round 4
// baseline (214.093 us; speedup 1.0000x reference)
//
#include <hip/hip_runtime.h>
#include <hip/hip_cooperative_groups.h>

namespace cg = cooperative_groups;

// Problem constants (match reference file)
#define Bn  4
#define Cn  3
#define Hn  224
#define Wn  224
#define Kn  196
#define En  768
#define HW  (Hn * Wn)            // 50176 pixels per (b,c) plane
#define BPB 49                   // pooling blocks per batch
#define NPOOL (Bn * BPB)         // 196 pooling blocks
#define KC  (Kn * Cn)            // 588 histogram slots per batch
#define NBLK (Bn * Kn)           // 784 total blocks (one per (b,k) in phase 2)

// Single cooperative kernel, 784 blocks x 256 threads.
// Phase 1 (blocks 0..195): each block owns 1024 contiguous pixels of one
//   batch (int4/float4 loads), builds a 588-float LDS histogram via
//   ds_add_f32 atomics, stores it as this block's private partials row.
// grid.sync()
// Phase 2 (all 784 blocks): block = one (b,k); gather the 49 partials x 3
//   channels (L2-warm), reduce in LDS, emit 768 outputs as float4 stores.
__global__ __launch_bounds__(256) void fused_kernel(
    const float* __restrict__ img,       // (B,C,H,W)
    const int*   __restrict__ seg,       // (B,H,W)
    const float* __restrict__ Wm,        // (C,E)
    const float* __restrict__ bias,      // (E,)
    float*       __restrict__ out,       // (B,K,E)
    float*       __restrict__ partials)  // (NPOOL, KC) in d_ws
{
    __shared__ float sh[KC];     // phase 1: histogram; phase 2: reuse [0:147)
    __shared__ float sums[3];
    const int tid = threadIdx.x;

    // ---------------- Phase 1: segmented partial sums ----------------
    if (blockIdx.x < NPOOL) {
        for (int i = tid; i < KC; i += 256) sh[i] = 0.0f;
        __syncthreads();

        const int batch = blockIdx.x / BPB;
        const int blk   = blockIdx.x % BPB;
        const int p4    = blk * 256 + tid;   // float4 index within a plane

        const int4*   seg4 = (const int4*)(seg + (size_t)batch * HW);
        const float4* im   = (const float4*)(img + (size_t)batch * Cn * HW);

        const int4   s  = seg4[p4];
        const float4 v0 = im[p4];                 // c = 0 plane
        const float4 v1 = im[HW / 4 + p4];        // c = 1 plane
        const float4 v2 = im[2 * (HW / 4) + p4];  // c = 2 plane

        atomicAdd(&sh[s.x * 3 + 0], v0.x);
        atomicAdd(&sh[s.x * 3 + 1], v1.x);
        atomicAdd(&sh[s.x * 3 + 2], v2.x);
        atomicAdd(&sh[s.y * 3 + 0], v0.y);
        atomicAdd(&sh[s.y * 3 + 1], v1.y);
        atomicAdd(&sh[s.y * 3 + 2], v2.y);
        atomicAdd(&sh[s.z * 3 + 0], v0.z);
        atomicAdd(&sh[s.z * 3 + 1], v1.z);
        atomicAdd(&sh[s.z * 3 + 2], v2.z);
        atomicAdd(&sh[s.w * 3 + 0], v0.w);
        atomicAdd(&sh[s.w * 3 + 1], v1.w);
        atomicAdd(&sh[s.w * 3 + 2], v2.w);
        __syncthreads();

        float4* dst = (float4*)(partials + (size_t)blockIdx.x * KC);
        if (tid < KC / 4) dst[tid] = ((const float4*)sh)[tid];   // 147 float4
    }

    __threadfence();             // release partials device-wide (cross-XCD)
    cg::this_grid().sync();      // all 784 blocks
    __syncthreads();             // safe to re-use sh[] after phase 1

    // ---------------- Phase 2: reduce + embed ----------------
    const int b = blockIdx.x / Kn;
    const int k = blockIdx.x % Kn;

    if (tid < BPB * 3) {
        const int j = tid / 3;   // partial row within this batch
        const int c = tid % 3;   // channel
        sh[tid] = partials[(size_t)(b * BPB + j) * KC + k * 3 + c];
    }
    __syncthreads();

    if (tid < 3) {
        float s = 0.0f;
        #pragma unroll
        for (int j = 0; j < BPB; ++j) s += sh[j * 3 + tid];
        sums[tid] = s * (1.0f / (float)HW);
    }
    __syncthreads();

    if (tid < En / 4) {          // 192 active lanes, one float4 each
        const float p0 = sums[0];
        const float p1 = sums[1];
        const float p2 = sums[2];

        const float4 w0 = ((const float4*)(Wm          ))[tid];
        const float4 w1 = ((const float4*)(Wm +     En ))[tid];
        const float4 w2 = ((const float4*)(Wm + 2 * En ))[tid];
        const float4 bb = ((const float4*)bias)[tid];

        float4 r;
        r.x = p0 * w0.x + p1 * w1.x + p2 * w2.x + bb.x;
        r.y = p0 * w0.y + p1 * w1.y + p2 * w2.y + bb.y;
        r.z = p0 * w0.z + p1 * w1.z + p2 * w2.z + bb.z;
        r.w = p0 * w0.w + p1 * w1.w + p2 * w2.w + bb.w;
        ((float4*)out)[(size_t)blockIdx.x * (En / 4) + tid] = r;
    }
}

extern "C" void kernel_launch(void* const* d_in, const int* in_sizes, int n_in,
                              void* d_out, int out_size, void* d_ws, size_t ws_size,
                              hipStream_t stream) {
    const float* img  = (const float*)d_in[0];  // (4,3,224,224) fp32
    const int*   seg  = (const int*)  d_in[1];  // (4,224,224) int32
    const float* Wm   = (const float*)d_in[2];  // (3,768) fp32
    const float* bias = (const float*)d_in[3];  // (768,) fp32
    float* out      = (float*)d_out;            // (4,196,768) fp32
    float* partials = (float*)d_ws;             // (196,588) floats, fully overwritten

    void* args[] = {(void*)&img, (void*)&seg, (void*)&Wm, (void*)&bias,
                    (void*)&out, (void*)&partials};
    (void)hipLaunchCooperativeKernel((const void*)fused_kernel, dim3(NBLK),
                                     dim3(256), args, 0, stream);
}

// Round 5
// 67.112 us; speedup vs baseline: 3.1901x; 3.1901x over previous
//
#include <hip/hip_runtime.h>

// Problem constants (match reference file)
#define Bn  4
#define Cn  3
#define Hn  224
#define Wn  224
#define Kn  196
#define En  768
#define HW  (Hn * Wn)            // 50176 pixels per (b,c) plane
#define BPB 49                   // pooling blocks per batch
#define NPOOL (Bn * BPB)         // 196 pooling blocks
#define KC  (Kn * Cn)            // 588 histogram slots per block

// partials layout: partials[((b*3 + c)*Kn + k)*BPB + j]
//   j = pooling block index within batch. Written scattered (stores,
//   fire-and-forget), read coalesced (49-float contiguous runs).

// Kernel 1: per-block segmented partial sums. Each block owns 1024
// contiguous pixels of one batch (256 threads x 4 pixels, int4/float4
// loads issued BEFORE the LDS zero so load latency overlaps the init).
// LDS histogram (588 floats, ds_add_f32), then transposed flush.
__global__ __launch_bounds__(256) void seg_pool_partial(
    const float* __restrict__ img,       // (B,C,H,W)
    const int*   __restrict__ seg,       // (B,H,W)
    float*       __restrict__ partials)  // (B,3,Kn,BPB)
{
    __shared__ float sh[KC];
    const int tid   = threadIdx.x;
    const int batch = blockIdx.x / BPB;
    const int blk   = blockIdx.x % BPB;
    const int p4    = blk * 256 + tid;   // float4 index within a plane

    const int4*   seg4 = (const int4*)(seg + (size_t)batch * HW);
    const float4* im   = (const float4*)(img + (size_t)batch * Cn * HW);

    // Loads first — latency overlaps LDS zero + barrier.
    const int4   s  = seg4[p4];
    const float4 v0 = im[p4];                 // c = 0 plane
    const float4 v1 = im[HW / 4 + p4];        // c = 1 plane
    const float4 v2 = im[2 * (HW / 4) + p4];  // c = 2 plane

    if (tid < KC / 4) ((float4*)sh)[tid] = make_float4(0.f, 0.f, 0.f, 0.f);
    __syncthreads();

    atomicAdd(&sh[s.x * 3 + 0], v0.x);
    atomicAdd(&sh[s.x * 3 + 1], v1.x);
    atomicAdd(&sh[s.x * 3 + 2], v2.x);
    atomicAdd(&sh[s.y * 3 + 0], v0.y);
    atomicAdd(&sh[s.y * 3 + 1], v1.y);
    atomicAdd(&sh[s.y * 3 + 2], v2.y);
    atomicAdd(&sh[s.z * 3 + 0], v0.z);
    atomicAdd(&sh[s.z * 3 + 1], v1.z);
    atomicAdd(&sh[s.z * 3 + 2], v2.z);
    atomicAdd(&sh[s.w * 3 + 0], v0.w);
    atomicAdd(&sh[s.w * 3 + 1], v1.w);
    atomicAdd(&sh[s.w * 3 + 2], v2.w);
    __syncthreads();

    // Transposed flush: sh[k*3+c] -> partials[((batch*3+c)*Kn + k)*BPB + blk]
    for (int i = tid; i < KC; i += 256) {
        const int k = i / 3;
        const int c = i % 3;
        partials[(((size_t)batch * 3 + c) * Kn + k) * BPB + blk] = sh[i];
    }
}

// Kernel 2: one block per (b,k), 192 threads = 3 waves. Wave w owns
// channel c=w: lane j loads partial j (coalesced 49-float run), 6-step
// shuffle reduction, then all 192 threads emit one float4 of output.
__global__ __launch_bounds__(192) void embed_kernel(
    const float* __restrict__ partials,  // (B,3,Kn,BPB)
    const float* __restrict__ Wm,        // (C,E)
    const float* __restrict__ bias,      // (E,)
    float*       __restrict__ out)       // (B,K,E)
{
    __shared__ float sums[3];
    const int b    = blockIdx.x / Kn;
    const int k    = blockIdx.x % Kn;
    const int tid  = threadIdx.x;
    const int wave = tid >> 6;           // 0..2 == channel
    const int lane = tid & 63;

    float v = 0.0f;
    if (lane < BPB)
        v = partials[(((size_t)b * 3 + wave) * Kn + k) * BPB + lane];
    #pragma unroll
    for (int off = 32; off > 0; off >>= 1) v += __shfl_down(v, off, 64);
    if (lane == 0) sums[wave] = v * (1.0f / (float)HW);
    __syncthreads();

    const float p0 = sums[0];
    const float p1 = sums[1];
    const float p2 = sums[2];

    const float4 w0 = ((const float4*)(Wm          ))[tid];
    const float4 w1 = ((const float4*)(Wm +     En ))[tid];
    const float4 w2 = ((const float4*)(Wm + 2 * En ))[tid];
    const float4 bb = ((const float4*)bias)[tid];

    float4 r;
    r.x = p0 * w0.x + p1 * w1.x + p2 * w2.x + bb.x;
    r.y = p0 * w0.y + p1 * w1.y + p2 * w2.y + bb.y;
    r.z = p0 * w0.z + p1 * w1.z + p2 * w2.z + bb.z;
    r.w = p0 * w0.w + p1 * w1.w + p2 * w2.w + bb.w;
    ((float4*)out)[(size_t)blockIdx.x * (En / 4) + tid] = r;
}

extern "C" void kernel_launch(void* const* d_in, const int* in_sizes, int n_in,
                              void* d_out, int out_size, void* d_ws, size_t ws_size,
                              hipStream_t stream) {
    const float* img  = (const float*)d_in[0];  // (4,3,224,224) fp32
    const int*   seg  = (const int*)  d_in[1];  // (4,224,224) int32
    const float* Wm   = (const float*)d_in[2];  // (3,768) fp32
    const float* bias = (const float*)d_in[3];  // (768,) fp32
    float* out      = (float*)d_out;            // (4,196,768) fp32
    float* partials = (float*)d_ws;             // (4,3,196,49) floats, fully overwritten

    seg_pool_partial<<<NPOOL, 256, 0, stream>>>(img, seg, partials);
    embed_kernel<<<Bn * Kn, 192, 0, stream>>>(partials, Wm, bias, out);
}